// Round 1
// baseline (509.407 us; speedup 1.0000x reference)
//
#include <hip/hip_runtime.h>
#include <cstdint>
#include <cstddef>

#define N_ROWS 16384   // B*T = 16*1024
#define KCODES 4096
#define DIM    256

// -------- kernel 1: inverse L2 norms of z rows and codebook rows --------
__global__ __launch_bounds__(256) void norms_kernel(
    const float* __restrict__ z, const float* __restrict__ cb,
    float* __restrict__ zinv, float* __restrict__ cinv)
{
    int wid  = blockIdx.x * 4 + (threadIdx.x >> 6);   // one wave per row
    int lane = threadIdx.x & 63;
    const float* src;
    float* dst;
    if (wid < N_ROWS) { src = z + (size_t)wid * DIM; dst = zinv + wid; }
    else {
        int r = wid - N_ROWS;
        src = cb + (size_t)r * DIM; dst = cinv + r;
    }
    float4 v = reinterpret_cast<const float4*>(src)[lane];  // 64 lanes * 4 = 256
    float s = v.x*v.x + v.y*v.y + v.z*v.z + v.w*v.w;
    #pragma unroll
    for (int m = 1; m <= 32; m <<= 1) s += __shfl_xor(s, m);
    if (lane == 0) *dst = 1.0f / fmaxf(sqrtf(s), 1e-12f);
}

// -------- kernel 2: fused fp32 GEMM (cosine sims) + gumbel + per-tile argmax --------
// grid: (32 col-tiles, 128 row-tiles), 256 threads, 128x128 tile, 8x8 per thread
__global__ __launch_bounds__(256) void gemm_argmax_kernel(
    const float* __restrict__ z, const float* __restrict__ cb,
    const float* __restrict__ u,
    const float* __restrict__ zinv, const float* __restrict__ cinv,
    float2* __restrict__ partial)   // [N_ROWS][32] (bestval, bestidx-as-float)
{
    __shared__ float As[32][132];   // [k][row], pad 4 -> rows stay 16B aligned
    __shared__ float Bs[32][132];

    const int t  = threadIdx.x;
    const int tx = t & 15;          // col group
    const int ty = t >> 4;          // row group
    const int bcol = blockIdx.x;    // 0..31
    const int brow = blockIdx.y;    // 0..127
    const int n0 = brow * 128;
    const int k0 = bcol * 128;

    const int lrow = t >> 3;        // 0..31
    const int c8   = t & 7;         // float4 column within 32-wide k-slab

    float sA[4], sB[4];
    const float* pA[4];
    const float* pB[4];
    #pragma unroll
    for (int i = 0; i < 4; ++i) {
        int ra = lrow + 32 * i;     // 0..127
        sA[i] = zinv[n0 + ra];
        pA[i] = z  + (size_t)(n0 + ra) * DIM + c8 * 4;
        sB[i] = cinv[k0 + ra];
        pB[i] = cb + (size_t)(k0 + ra) * DIM + c8 * 4;
    }

    float acc[8][8];
    #pragma unroll
    for (int i = 0; i < 8; ++i)
        #pragma unroll
        for (int j = 0; j < 8; ++j) acc[i][j] = 0.f;

    #pragma unroll 1
    for (int d0 = 0; d0 < DIM; d0 += 32) {
        #pragma unroll
        for (int i = 0; i < 4; ++i) {
            float4 va = *reinterpret_cast<const float4*>(pA[i] + d0);
            float4 vb = *reinterpret_cast<const float4*>(pB[i] + d0);
            int ra = lrow + 32 * i;
            As[c8*4+0][ra] = va.x * sA[i];
            As[c8*4+1][ra] = va.y * sA[i];
            As[c8*4+2][ra] = va.z * sA[i];
            As[c8*4+3][ra] = va.w * sA[i];
            Bs[c8*4+0][ra] = vb.x * sB[i];
            Bs[c8*4+1][ra] = vb.y * sB[i];
            Bs[c8*4+2][ra] = vb.z * sB[i];
            Bs[c8*4+3][ra] = vb.w * sB[i];
        }
        __syncthreads();
        #pragma unroll
        for (int kk = 0; kk < 32; ++kk) {
            float4 a0 = *reinterpret_cast<const float4*>(&As[kk][ty * 4]);
            float4 a1 = *reinterpret_cast<const float4*>(&As[kk][64 + ty * 4]);
            float4 b0 = *reinterpret_cast<const float4*>(&Bs[kk][tx * 4]);
            float4 b1 = *reinterpret_cast<const float4*>(&Bs[kk][64 + tx * 4]);
            float a[8] = {a0.x,a0.y,a0.z,a0.w,a1.x,a1.y,a1.z,a1.w};
            float b[8] = {b0.x,b0.y,b0.z,b0.w,b1.x,b1.y,b1.z,b1.w};
            #pragma unroll
            for (int i = 0; i < 8; ++i)
                #pragma unroll
                for (int j = 0; j < 8; ++j)
                    acc[i][j] = fmaf(a[i], b[j], acc[i][j]);
        }
        __syncthreads();
    }

    // epilogue: + gumbel, per-row argmax across this 128-col tile
    #pragma unroll
    for (int i = 0; i < 8; ++i) {
        int r  = ((i & 4) ? 64 : 0) + ty * 4 + (i & 3);
        int gn = n0 + r;
        float best = -3.0e38f;
        int   bidx = 0;
        #pragma unroll
        for (int jg = 0; jg < 2; ++jg) {
            int cbase = k0 + jg * 64 + tx * 4;
            float4 uu = *reinterpret_cast<const float4*>(&u[(size_t)gn * KCODES + cbase]);
            float uv[4] = {uu.x, uu.y, uu.z, uu.w};
            #pragma unroll
            for (int jj = 0; jj < 4; ++jj) {
                float g = -logf(-logf(uv[jj] + 1e-10f) + 1e-10f);
                float v = acc[i][jg * 4 + jj] + g;
                if (v > best) { best = v; bidx = cbase + jj; }  // ascending idx -> first max kept
            }
        }
        // reduce across the 16 tx lanes sharing this row (lanes (ty&3)*16 + tx)
        #pragma unroll
        for (int m = 1; m <= 8; m <<= 1) {
            float ov = __shfl_xor(best, m);
            int   oi = __shfl_xor(bidx, m);
            if (ov > best || (ov == best && oi < bidx)) { best = ov; bidx = oi; }
        }
        if (tx == 0) partial[(size_t)gn * 32 + bcol] = make_float2(best, (float)bidx);
    }
}

// -------- kernel 3: reduce 32 partials/row, gather codebook row, commitment partial --------
__global__ __launch_bounds__(256) void reduce_gather_kernel(
    const float2* __restrict__ partial,
    const float* __restrict__ cb, const float* __restrict__ z,
    float* __restrict__ zq, float* __restrict__ emb,
    float* __restrict__ idx_out, float* __restrict__ commit_part)
{
    int row  = blockIdx.x * 4 + (threadIdx.x >> 6);   // one wave per row
    int lane = threadIdx.x & 63;
    float v = -3.0e38f;
    int   bi = 0x7fffffff;
    if (lane < 32) {
        float2 p = partial[(size_t)row * 32 + lane];
        v = p.x; bi = (int)p.y;
    }
    #pragma unroll
    for (int m = 1; m <= 32; m <<= 1) {
        float ov = __shfl_xor(v, m);
        int   oi = __shfl_xor(bi, m);
        if (ov > v || (ov == v && oi < bi)) { v = ov; bi = oi; }
    }
    float4 c  = reinterpret_cast<const float4*>(cb + (size_t)bi * DIM)[lane];
    reinterpret_cast<float4*>(zq  + (size_t)row * DIM)[lane] = c;
    reinterpret_cast<float4*>(emb + (size_t)row * DIM)[lane] = c;
    float4 zz = reinterpret_cast<const float4*>(z + (size_t)row * DIM)[lane];
    float dx = c.x - zz.x, dy = c.y - zz.y, dz = c.z - zz.z, dw = c.w - zz.w;
    float s = dx*dx + dy*dy + dz*dz + dw*dw;
    #pragma unroll
    for (int m = 1; m <= 32; m <<= 1) s += __shfl_xor(s, m);
    if (lane == 0) {
        idx_out[row]     = (float)bi;
        commit_part[row] = s;
    }
}

// -------- kernel 4: scalars (commitment, entropy bonus, perplexity, entropy) --------
__global__ __launch_bounds__(256) void scalars_kernel(
    const float* __restrict__ commit_part, const float* __restrict__ usage,
    const int* __restrict__ step_ptr, float* __restrict__ out4)
{
    __shared__ float red[256];
    int t = threadIdx.x;

    float s = 0.f;
    for (int i = t; i < N_ROWS; i += 256) s += commit_part[i];
    red[t] = s; __syncthreads();
    for (int w = 128; w > 0; w >>= 1) { if (t < w) red[t] += red[t + w]; __syncthreads(); }
    float commitment = 0.5f * red[0] / 4194304.0f;   // mean over B*T*D
    __syncthreads();

    float us = 0.f;
    for (int i = t; i < KCODES; i += 256) us += usage[i];
    red[t] = us; __syncthreads();
    for (int w = 128; w > 0; w >>= 1) { if (t < w) red[t] += red[t + w]; __syncthreads(); }
    float usage_sum = red[0];
    __syncthreads();

    float e = 0.f;
    for (int i = t; i < KCODES; i += 256) {
        float p = (usage_sum > 0.f) ? usage[i] / (usage_sum + 1e-10f) : (1.0f / KCODES);
        e += p * logf(p + 1e-10f);
    }
    red[t] = e; __syncthreads();
    for (int w = 128; w > 0; w >>= 1) { if (t < w) red[t] += red[t + w]; __syncthreads(); }

    if (t == 0) {
        float entropy = -red[0];
        int step_after = step_ptr[0] + 1;
        float bonus_w = 0.05f * (1.0f - (float)step_after / 20000.0f);
        float eb = (step_after < 20000) ? (-bonus_w * entropy) : 0.0f;
        out4[0] = commitment;
        out4[1] = eb;
        out4[2] = expf(entropy);
        out4[3] = entropy;
    }
}

extern "C" void kernel_launch(void* const* d_in, const int* in_sizes, int n_in,
                              void* d_out, int out_size, void* d_ws, size_t ws_size,
                              hipStream_t stream)
{
    const float* z     = (const float*)d_in[0];   // [16,1024,256]
    const float* u     = (const float*)d_in[1];   // [16,1024,4096]
    const float* cb    = (const float*)d_in[2];   // [4096,256]
    const float* usage = (const float*)d_in[3];   // [4096]
    const int*   step  = (const int*)d_in[4];     // scalar

    float* out  = (float*)d_out;
    float* zq   = out;                 // 4194304
    float* emb  = out + 4194304;       // 4194304
    float* idxo = out + 8388608;       // 16384
    float* scal = out + 8404992;       // 4

    float*  ws          = (float*)d_ws;
    float*  zinv        = ws;                    // 16384
    float*  cinv        = ws + 16384;            // 4096
    float*  commit_part = ws + 20480;            // 16384
    float2* partial     = (float2*)(ws + 36864); // 16384*32 float2 (4 MB)

    hipLaunchKernelGGL(norms_kernel, dim3(5120), dim3(256), 0, stream, z, cb, zinv, cinv);
    hipLaunchKernelGGL(gemm_argmax_kernel, dim3(32, 128), dim3(256), 0, stream,
                       z, cb, u, zinv, cinv, partial);
    hipLaunchKernelGGL(reduce_gather_kernel, dim3(4096), dim3(256), 0, stream,
                       partial, cb, z, zq, emb, idxo, commit_part);
    hipLaunchKernelGGL(scalars_kernel, dim3(1), dim3(256), 0, stream,
                       commit_part, usage, step, scal);
}

// Round 2
// 390.719 us; speedup vs baseline: 1.3038x; 1.3038x over previous
//
#include <hip/hip_runtime.h>
#include <cstdint>
#include <cstddef>

#define N_ROWS 16384   // B*T
#define KCODES 4096
#define DIM    256

typedef _Float16 f16x8 __attribute__((ext_vector_type(8)));
typedef float    f32x4 __attribute__((ext_vector_type(4)));

__device__ inline void gload16(const void* g, void* l) {
    __builtin_amdgcn_global_load_lds((const __attribute__((address_space(1))) void*)g,
                                     (__attribute__((address_space(3))) void*)l, 16, 0, 0);
}

// -------- kernel 1: inverse L2 norms of z rows and codebook rows --------
__global__ __launch_bounds__(256) void norms_kernel(
    const float* __restrict__ z, const float* __restrict__ cb,
    float* __restrict__ zinv, float* __restrict__ cinv)
{
    int wid  = blockIdx.x * 4 + (threadIdx.x >> 6);
    int lane = threadIdx.x & 63;
    const float* src;
    float* dst;
    if (wid < N_ROWS) { src = z + (size_t)wid * DIM; dst = zinv + wid; }
    else {
        int r = wid - N_ROWS;
        src = cb + (size_t)r * DIM; dst = cinv + r;
    }
    float4 v = reinterpret_cast<const float4*>(src)[lane];
    float s = v.x*v.x + v.y*v.y + v.z*v.z + v.w*v.w;
    #pragma unroll
    for (int m = 1; m <= 32; m <<= 1) s += __shfl_xor(s, m);
    if (lane == 0) *dst = 1.0f / fmaxf(sqrtf(s), 1e-12f);
}

// -------- kernel 2: normalize, scale x16, f16 hi/lo split, fragment-ordered layout --------
// grid (kt=4, ntiles). Tile = 128 rows x 64 k, layout [i(8)][kk(2)][lane(64)][8 f16].
__global__ __launch_bounds__(256) void prep_kernel(
    const float* __restrict__ src, const float* __restrict__ inv,
    _Float16* __restrict__ ghi, _Float16* __restrict__ glo)
{
    const int kt = blockIdx.x, btile = blockIdx.y;
    const int t = threadIdx.x, lane = t & 63, wid = t >> 6;
    #pragma unroll
    for (int fi = 0; fi < 4; ++fi) {
        int frag = wid * 4 + fi;
        int i = frag >> 1, kk = frag & 1;
        int r  = btile * 128 + i * 16 + (lane & 15);
        int k0 = kt * 64 + kk * 32 + ((lane >> 4) << 3);
        const float4* p = reinterpret_cast<const float4*>(src + (size_t)r * DIM + k0);
        float4 v0 = p[0], v1 = p[1];
        float s = inv[r] * 16.0f;
        float x[8] = {v0.x*s, v0.y*s, v0.z*s, v0.w*s, v1.x*s, v1.y*s, v1.z*s, v1.w*s};
        f16x8 h, l;
        #pragma unroll
        for (int e = 0; e < 8; ++e) {
            _Float16 he = (_Float16)x[e];
            h[e] = he;
            l[e] = (_Float16)((x[e] - (float)he) * 4096.0f);
        }
        size_t base = ((size_t)(btile * 4 + kt)) * 8192 + (size_t)(i * 2 + kk) * 512 + lane * 8;
        *reinterpret_cast<f16x8*>(ghi + base) = h;
        *reinterpret_cast<f16x8*>(glo + base) = l;
    }
}

// -------- kernel 3: MFMA split-precision GEMM + gumbel + per-tile argmax --------
#define A_HI 0
#define A_LO 16384
#define B_HI 32768
#define B_LO 49152

__global__ __launch_bounds__(256, 2) void gemm_argmax_kernel(
    const _Float16* __restrict__ zhi, const _Float16* __restrict__ zlo,
    const _Float16* __restrict__ chi, const _Float16* __restrict__ clo,
    const float* __restrict__ u,
    float2* __restrict__ partial)   // [N_ROWS][32]
{
    __shared__ __align__(16) char lds[65536];

    // bijective XCD swizzle: 4096 blocks % 8 == 0
    int bid = blockIdx.x;
    int swz = (bid & 7) * 512 + (bid >> 3);
    const int brow = swz >> 5;      // 0..127
    const int bcol = swz & 31;      // 0..31

    const int t = threadIdx.x, lane = t & 63;
    const int wave = t >> 6, wm = wave >> 1, wn = wave & 1;

    f32x4 accm[4][4], accc[4][4];
    #pragma unroll
    for (int i = 0; i < 4; ++i)
        #pragma unroll
        for (int j = 0; j < 4; ++j) {
            accm[i][j] = (f32x4){0.f,0.f,0.f,0.f};
            accc[i][j] = (f32x4){0.f,0.f,0.f,0.f};
        }

    #pragma unroll 1
    for (int kt = 0; kt < 4; ++kt) {
        const _Float16* gz_hi = zhi + ((size_t)(brow * 4 + kt)) * 8192;
        const _Float16* gz_lo = zlo + ((size_t)(brow * 4 + kt)) * 8192;
        const _Float16* gc_hi = chi + ((size_t)(bcol * 4 + kt)) * 8192;
        const _Float16* gc_lo = clo + ((size_t)(bcol * 4 + kt)) * 8192;
        #pragma unroll
        for (int c = 0; c < 4; ++c) {
            int go = c * 2048 + t * 8;       // halfs
            int lo = c * 4096 + t * 16;      // bytes
            gload16(gz_hi + go, lds + A_HI + lo);
            gload16(gz_lo + go, lds + A_LO + lo);
            gload16(gc_hi + go, lds + B_HI + lo);
            gload16(gc_lo + go, lds + B_LO + lo);
        }
        __syncthreads();

        #pragma unroll
        for (int kk = 0; kk < 2; ++kk) {
            f16x8 ah[4], al[4], bh[4], bl[4];
            #pragma unroll
            for (int i = 0; i < 4; ++i) {
                int ao = (((wm * 4 + i) * 2 + kk) << 10) + lane * 16;
                ah[i] = *reinterpret_cast<const f16x8*>(lds + A_HI + ao);
                al[i] = *reinterpret_cast<const f16x8*>(lds + A_LO + ao);
            }
            #pragma unroll
            for (int j = 0; j < 4; ++j) {
                int bo = (((wn * 4 + j) * 2 + kk) << 10) + lane * 16;
                bh[j] = *reinterpret_cast<const f16x8*>(lds + B_HI + bo);
                bl[j] = *reinterpret_cast<const f16x8*>(lds + B_LO + bo);
            }
            #pragma unroll
            for (int i = 0; i < 4; ++i)
                #pragma unroll
                for (int j = 0; j < 4; ++j) {
                    accm[i][j] = __builtin_amdgcn_mfma_f32_16x16x32_f16(ah[i], bh[j], accm[i][j], 0, 0, 0);
                    accc[i][j] = __builtin_amdgcn_mfma_f32_16x16x32_f16(ah[i], bl[j], accc[i][j], 0, 0, 0);
                    accc[i][j] = __builtin_amdgcn_mfma_f32_16x16x32_f16(al[i], bh[j], accc[i][j], 0, 0, 0);
                }
        }
        __syncthreads();
    }

    // epilogue: S = (accm + accc/4096)/256 + gumbel; per-row argmax over 128 cols
    float2* sbest = reinterpret_cast<float2*>(lds);   // [128][2]
    const float isc = 1.0f / 4096.0f;
    const float osc = 1.0f / 256.0f;
    const int l15 = lane & 15;

    #pragma unroll
    for (int i = 0; i < 4; ++i) {
        #pragma unroll
        for (int q = 0; q < 4; ++q) {
            int rloc = wm * 64 + i * 16 + ((lane >> 4) << 2) + q;
            int grow = brow * 128 + rloc;
            const float* urow = u + (size_t)grow * KCODES + bcol * 128 + wn * 64 + l15;
            float best = -3.0e38f;
            int bidx = 1 << 30;
            #pragma unroll
            for (int j = 0; j < 4; ++j) {
                float s = (accm[i][j][q] + accc[i][j][q] * isc) * osc;
                float uu = urow[j * 16];
                float y = -__logf(uu + 1e-10f);           // hw log: |dg| ~1e-7
                float g = -logf(y + 1e-10f);              // libm: numpy-ulp regime
                float v = s + g;
                int ci = bcol * 128 + wn * 64 + j * 16 + l15;
                if (v > best || (v == best && ci < bidx)) { best = v; bidx = ci; }
            }
            #pragma unroll
            for (int m = 1; m <= 8; m <<= 1) {
                float ov = __shfl_xor(best, m);
                int   oi = __shfl_xor(bidx, m);
                if (ov > best || (ov == best && oi < bidx)) { best = ov; bidx = oi; }
            }
            if (l15 == 0) sbest[rloc * 2 + wn] = make_float2(best, (float)bidx);
        }
    }
    __syncthreads();
    if (t < 128) {
        float2 a = sbest[t * 2], b = sbest[t * 2 + 1];
        float2 w = (b.x > a.x || (b.x == a.x && b.y < a.y)) ? b : a;
        partial[(size_t)(brow * 128 + t) * 32 + bcol] = w;
    }
}

// -------- kernel 4: reduce 32 partials/row, gather codebook row, commitment partial --------
__global__ __launch_bounds__(256) void reduce_gather_kernel(
    const float2* __restrict__ partial,
    const float* __restrict__ cb, const float* __restrict__ z,
    float* __restrict__ zq, float* __restrict__ emb,
    float* __restrict__ idx_out, float* __restrict__ commit_part)
{
    int row  = blockIdx.x * 4 + (threadIdx.x >> 6);
    int lane = threadIdx.x & 63;
    float v = -3.0e38f;
    int   bi = 0x7fffffff;
    if (lane < 32) {
        float2 p = partial[(size_t)row * 32 + lane];
        v = p.x; bi = (int)p.y;
    }
    #pragma unroll
    for (int m = 1; m <= 32; m <<= 1) {
        float ov = __shfl_xor(v, m);
        int   oi = __shfl_xor(bi, m);
        if (ov > v || (ov == v && oi < bi)) { v = ov; bi = oi; }
    }
    float4 c  = reinterpret_cast<const float4*>(cb + (size_t)bi * DIM)[lane];
    reinterpret_cast<float4*>(zq  + (size_t)row * DIM)[lane] = c;
    reinterpret_cast<float4*>(emb + (size_t)row * DIM)[lane] = c;
    float4 zz = reinterpret_cast<const float4*>(z + (size_t)row * DIM)[lane];
    float dx = c.x - zz.x, dy = c.y - zz.y, dz = c.z - zz.z, dw = c.w - zz.w;
    float s = dx*dx + dy*dy + dz*dz + dw*dw;
    #pragma unroll
    for (int m = 1; m <= 32; m <<= 1) s += __shfl_xor(s, m);
    if (lane == 0) {
        idx_out[row]     = (float)bi;
        commit_part[row] = s;
    }
}

// -------- kernel 5: scalars --------
__global__ __launch_bounds__(256) void scalars_kernel(
    const float* __restrict__ commit_part, const float* __restrict__ usage,
    const int* __restrict__ step_ptr, float* __restrict__ out4)
{
    __shared__ float red[256];
    int t = threadIdx.x;

    float s = 0.f;
    for (int i = t; i < N_ROWS; i += 256) s += commit_part[i];
    red[t] = s; __syncthreads();
    for (int w = 128; w > 0; w >>= 1) { if (t < w) red[t] += red[t + w]; __syncthreads(); }
    float commitment = 0.5f * red[0] / 4194304.0f;
    __syncthreads();

    float us = 0.f;
    for (int i = t; i < KCODES; i += 256) us += usage[i];
    red[t] = us; __syncthreads();
    for (int w = 128; w > 0; w >>= 1) { if (t < w) red[t] += red[t + w]; __syncthreads(); }
    float usage_sum = red[0];
    __syncthreads();

    float e = 0.f;
    for (int i = t; i < KCODES; i += 256) {
        float p = (usage_sum > 0.f) ? usage[i] / (usage_sum + 1e-10f) : (1.0f / KCODES);
        e += p * logf(p + 1e-10f);
    }
    red[t] = e; __syncthreads();
    for (int w = 128; w > 0; w >>= 1) { if (t < w) red[t] += red[t + w]; __syncthreads(); }

    if (t == 0) {
        float entropy = -red[0];
        int step_after = step_ptr[0] + 1;
        float bonus_w = 0.05f * (1.0f - (float)step_after / 20000.0f);
        float eb = (step_after < 20000) ? (-bonus_w * entropy) : 0.0f;
        out4[0] = commitment;
        out4[1] = eb;
        out4[2] = expf(entropy);
        out4[3] = entropy;
    }
}

extern "C" void kernel_launch(void* const* d_in, const int* in_sizes, int n_in,
                              void* d_out, int out_size, void* d_ws, size_t ws_size,
                              hipStream_t stream)
{
    const float* z     = (const float*)d_in[0];
    const float* u     = (const float*)d_in[1];
    const float* cb    = (const float*)d_in[2];
    const float* usage = (const float*)d_in[3];
    const int*   step  = (const int*)d_in[4];

    float* out  = (float*)d_out;
    float* zq   = out;                 // 4194304
    float* emb  = out + 4194304;       // 4194304
    float* idxo = out + 8388608;       // 16384
    float* scal = out + 8404992;       // 4

    // prep arrays live in d_out's first 20 MB (dead until reduce_gather rewrites it)
    _Float16* zhi = (_Float16*)out;            // 8 MB
    _Float16* zlo = zhi + 4194304;             // 8 MB
    _Float16* chi = zlo + 4194304;             // 2 MB
    _Float16* clo = chi + 1048576;             // 2 MB

    float*  ws          = (float*)d_ws;
    float*  zinv        = ws;                    // 16384
    float*  cinv        = ws + 16384;            // 4096
    float*  commit_part = ws + 20480;            // 16384
    float2* partial     = (float2*)(ws + 36864); // 16384*32 float2 (4 MB)

    hipLaunchKernelGGL(norms_kernel, dim3(5120), dim3(256), 0, stream, z, cb, zinv, cinv);
    hipLaunchKernelGGL(prep_kernel, dim3(4, 128), dim3(256), 0, stream, z,  zinv, zhi, zlo);
    hipLaunchKernelGGL(prep_kernel, dim3(4, 32),  dim3(256), 0, stream, cb, cinv, chi, clo);
    hipLaunchKernelGGL(gemm_argmax_kernel, dim3(4096), dim3(256), 0, stream,
                       zhi, zlo, chi, clo, u, partial);
    hipLaunchKernelGGL(reduce_gather_kernel, dim3(4096), dim3(256), 0, stream,
                       partial, cb, z, zq, emb, idxo, commit_part);
    hipLaunchKernelGGL(scalars_kernel, dim3(1), dim3(256), 0, stream,
                       commit_part, usage, step, scal);
}

// Round 3
// 390.151 us; speedup vs baseline: 1.3057x; 1.0015x over previous
//
#include <hip/hip_runtime.h>
#include <cstdint>
#include <cstddef>

#define N_ROWS 16384   // B*T
#define KCODES 4096
#define DIM    256

typedef _Float16 f16x8 __attribute__((ext_vector_type(8)));
typedef float    f32x4 __attribute__((ext_vector_type(4)));

__device__ inline void gload16(const void* g, void* l) {
    __builtin_amdgcn_global_load_lds((const __attribute__((address_space(1))) void*)g,
                                     (__attribute__((address_space(3))) void*)l, 16, 0, 0);
}

// -------- kernel 1: inverse L2 norms of z rows and codebook rows --------
__global__ __launch_bounds__(256) void norms_kernel(
    const float* __restrict__ z, const float* __restrict__ cb,
    float* __restrict__ zinv, float* __restrict__ cinv)
{
    int wid  = blockIdx.x * 4 + (threadIdx.x >> 6);
    int lane = threadIdx.x & 63;
    const float* src;
    float* dst;
    if (wid < N_ROWS) { src = z + (size_t)wid * DIM; dst = zinv + wid; }
    else {
        int r = wid - N_ROWS;
        src = cb + (size_t)r * DIM; dst = cinv + r;
    }
    float4 v = reinterpret_cast<const float4*>(src)[lane];
    float s = v.x*v.x + v.y*v.y + v.z*v.z + v.w*v.w;
    #pragma unroll
    for (int m = 1; m <= 32; m <<= 1) s += __shfl_xor(s, m);
    if (lane == 0) *dst = 1.0f / fmaxf(sqrtf(s), 1e-12f);
}

// -------- kernel 2: normalize, x16 scale, f16 hi/lo split, fragment order --------
// K-tile = 32. Tile (btile, kt) = 128 rows x 32 k. Layout: [frag(8)][lane(64)][8 f16].
__global__ __launch_bounds__(256) void prep_kernel(
    const float* __restrict__ src, const float* __restrict__ inv,
    _Float16* __restrict__ ghi, _Float16* __restrict__ glo)
{
    const int kt = blockIdx.x;        // 0..7
    const int btile = blockIdx.y;
    const int t = threadIdx.x, lane = t & 63, wid = t >> 6;
    #pragma unroll
    for (int fi = 0; fi < 2; ++fi) {
        int frag = wid * 2 + fi;      // 0..7 (16-row groups)
        int r  = btile * 128 + frag * 16 + (lane & 15);
        int k0 = kt * 32 + ((lane >> 4) << 3);
        const float4* p = reinterpret_cast<const float4*>(src + (size_t)r * DIM + k0);
        float4 v0 = p[0], v1 = p[1];
        float s = inv[r] * 16.0f;
        float x[8] = {v0.x*s, v0.y*s, v0.z*s, v0.w*s, v1.x*s, v1.y*s, v1.z*s, v1.w*s};
        f16x8 h, l;
        #pragma unroll
        for (int e = 0; e < 8; ++e) {
            _Float16 he = (_Float16)x[e];
            h[e] = he;
            l[e] = (_Float16)((x[e] - (float)he) * 4096.0f);
        }
        size_t base = ((size_t)(btile * 8 + kt)) * 4096 + (size_t)frag * 512 + lane * 8;
        *reinterpret_cast<f16x8*>(ghi + base) = h;
        *reinterpret_cast<f16x8*>(glo + base) = l;
    }
}

// -------- kernel 3: MFMA split-precision GEMM + gumbel + per-tile argmax --------
// 128x128 tile, BK=32, double-buffered LDS (2 x 32KB), 2-phase schedule.
#define BUFSZ 32768

__global__ __launch_bounds__(256, 2) void gemm_argmax_kernel(
    const _Float16* __restrict__ zhi, const _Float16* __restrict__ zlo,
    const _Float16* __restrict__ chi, const _Float16* __restrict__ clo,
    const float* __restrict__ u,
    float2* __restrict__ partial)   // [N_ROWS][32]
{
    __shared__ __align__(16) char lds[65536];

    // bijective XCD swizzle (4096 % 8 == 0): contiguous 512-block chunk per XCD
    int bid = blockIdx.x;
    int swz = (bid & 7) * 512 + (bid >> 3);
    const int brow = swz >> 5;      // 0..127
    const int bcol = swz & 31;      // 0..31

    const int t = threadIdx.x, lane = t & 63;
    const int wave = t >> 6, wm = wave >> 1, wn = wave & 1;

    const _Float16* zh = zhi + (size_t)(brow * 8) * 4096;
    const _Float16* zl = zlo + (size_t)(brow * 8) * 4096;
    const _Float16* ch = chi + (size_t)(bcol * 8) * 4096;
    const _Float16* cl = clo + (size_t)(bcol * 8) * 4096;

    auto stage = [&](int p, int kt) {
        char* dst = lds + p * BUFSZ;
        #pragma unroll
        for (int c = 0; c < 2; ++c) {
            int frag = wave * 2 + c;                 // 0..7, wave-uniform
            int go = kt * 4096 + frag * 512 + lane * 8;   // halfs
            int lo = frag * 1024 + lane * 16;             // bytes
            gload16(zh + go, dst + 0     + lo);
            gload16(zl + go, dst + 8192  + lo);
            gload16(ch + go, dst + 16384 + lo);
            gload16(cl + go, dst + 24576 + lo);
        }
    };

    f32x4 accm[4][4], accc[4][4];
    #pragma unroll
    for (int i = 0; i < 4; ++i)
        #pragma unroll
        for (int j = 0; j < 4; ++j) {
            accm[i][j] = (f32x4){0.f,0.f,0.f,0.f};
            accc[i][j] = (f32x4){0.f,0.f,0.f,0.f};
        }

    stage(0, 0);
    __syncthreads();   // vmcnt(0) drain + barrier: buf0 ready

    #pragma unroll 2
    for (int kt = 0; kt < 8; ++kt) {
        const int p = kt & 1;
        if (kt < 7) stage(p ^ 1, kt + 1);      // prefetch flies under compute

        const char* buf = lds + p * BUFSZ;
        f16x8 ah[4], al[4], bh[4], bl[4];
        #pragma unroll
        for (int i = 0; i < 4; ++i) {
            int ao = (wm * 4 + i) * 1024 + lane * 16;
            ah[i] = *reinterpret_cast<const f16x8*>(buf + ao);
            al[i] = *reinterpret_cast<const f16x8*>(buf + 8192 + ao);
            int bo = (wn * 4 + i) * 1024 + lane * 16;
            bh[i] = *reinterpret_cast<const f16x8*>(buf + 16384 + bo);
            bl[i] = *reinterpret_cast<const f16x8*>(buf + 24576 + bo);
        }
        #pragma unroll
        for (int i = 0; i < 4; ++i)
            #pragma unroll
            for (int j = 0; j < 4; ++j) {
                accm[i][j] = __builtin_amdgcn_mfma_f32_16x16x32_f16(ah[i], bh[j], accm[i][j], 0, 0, 0);
                accc[i][j] = __builtin_amdgcn_mfma_f32_16x16x32_f16(ah[i], bl[j], accc[i][j], 0, 0, 0);
                accc[i][j] = __builtin_amdgcn_mfma_f32_16x16x32_f16(al[i], bh[j], accc[i][j], 0, 0, 0);
            }
        __syncthreads();   // drains prefetch vmcnt + protects buf[p^1] overwrite
    }

    // epilogue: S = (accm + accc/4096)/256 + gumbel; per-row argmax over 128 cols
    float2* sbest = reinterpret_cast<float2*>(lds);   // [128][2]
    const float isc = 1.0f / 4096.0f;
    const float osc = 1.0f / 256.0f;
    const int l15 = lane & 15;

    #pragma unroll
    for (int i = 0; i < 4; ++i) {
        #pragma unroll
        for (int q = 0; q < 4; ++q) {
            int rloc = wm * 64 + i * 16 + ((lane >> 4) << 2) + q;
            int grow = brow * 128 + rloc;
            const float* urow = u + (size_t)grow * KCODES + bcol * 128 + wn * 64 + l15;
            float best = -3.0e38f;
            int bidx = 1 << 30;
            #pragma unroll
            for (int j = 0; j < 4; ++j) {
                float s = (accm[i][j][q] + accc[i][j][q] * isc) * osc;
                float uu = urow[j * 16];
                float y = -__logf(uu + 1e-10f);
                float g = -__logf(y + 1e-10f);
                float v = s + g;
                int ci = bcol * 128 + wn * 64 + j * 16 + l15;
                if (v > best || (v == best && ci < bidx)) { best = v; bidx = ci; }
            }
            #pragma unroll
            for (int m = 1; m <= 8; m <<= 1) {
                float ov = __shfl_xor(best, m);
                int   oi = __shfl_xor(bidx, m);
                if (ov > best || (ov == best && oi < bidx)) { best = ov; bidx = oi; }
            }
            if (l15 == 0) sbest[rloc * 2 + wn] = make_float2(best, (float)bidx);
        }
    }
    __syncthreads();
    if (t < 128) {
        float2 a = sbest[t * 2], b = sbest[t * 2 + 1];
        float2 w = (b.x > a.x || (b.x == a.x && b.y < a.y)) ? b : a;
        partial[(size_t)(brow * 128 + t) * 32 + bcol] = w;
    }
}

// -------- kernel 4: reduce 32 partials/row, gather codebook row, commitment partial --------
__global__ __launch_bounds__(256) void reduce_gather_kernel(
    const float2* __restrict__ partial,
    const float* __restrict__ cb, const float* __restrict__ z,
    float* __restrict__ zq, float* __restrict__ emb,
    float* __restrict__ idx_out, float* __restrict__ commit_part)
{
    int row  = blockIdx.x * 4 + (threadIdx.x >> 6);
    int lane = threadIdx.x & 63;
    float v = -3.0e38f;
    int   bi = 0x7fffffff;
    if (lane < 32) {
        float2 p = partial[(size_t)row * 32 + lane];
        v = p.x; bi = (int)p.y;
    }
    #pragma unroll
    for (int m = 1; m <= 32; m <<= 1) {
        float ov = __shfl_xor(v, m);
        int   oi = __shfl_xor(bi, m);
        if (ov > v || (ov == v && oi < bi)) { v = ov; bi = oi; }
    }
    float4 c  = reinterpret_cast<const float4*>(cb + (size_t)bi * DIM)[lane];
    reinterpret_cast<float4*>(zq  + (size_t)row * DIM)[lane] = c;
    reinterpret_cast<float4*>(emb + (size_t)row * DIM)[lane] = c;
    float4 zz = reinterpret_cast<const float4*>(z + (size_t)row * DIM)[lane];
    float dx = c.x - zz.x, dy = c.y - zz.y, dz = c.z - zz.z, dw = c.w - zz.w;
    float s = dx*dx + dy*dy + dz*dz + dw*dw;
    #pragma unroll
    for (int m = 1; m <= 32; m <<= 1) s += __shfl_xor(s, m);
    if (lane == 0) {
        idx_out[row]     = (float)bi;
        commit_part[row] = s;
    }
}

// -------- kernel 5: scalars --------
__global__ __launch_bounds__(256) void scalars_kernel(
    const float* __restrict__ commit_part, const float* __restrict__ usage,
    const int* __restrict__ step_ptr, float* __restrict__ out4)
{
    __shared__ float red[256];
    int t = threadIdx.x;

    float s = 0.f;
    for (int i = t; i < N_ROWS; i += 256) s += commit_part[i];
    red[t] = s; __syncthreads();
    for (int w = 128; w > 0; w >>= 1) { if (t < w) red[t] += red[t + w]; __syncthreads(); }
    float commitment = 0.5f * red[0] / 4194304.0f;
    __syncthreads();

    float us = 0.f;
    for (int i = t; i < KCODES; i += 256) us += usage[i];
    red[t] = us; __syncthreads();
    for (int w = 128; w > 0; w >>= 1) { if (t < w) red[t] += red[t + w]; __syncthreads(); }
    float usage_sum = red[0];
    __syncthreads();

    float e = 0.f;
    for (int i = t; i < KCODES; i += 256) {
        float p = (usage_sum > 0.f) ? usage[i] / (usage_sum + 1e-10f) : (1.0f / KCODES);
        e += p * logf(p + 1e-10f);
    }
    red[t] = e; __syncthreads();
    for (int w = 128; w > 0; w >>= 1) { if (t < w) red[t] += red[t + w]; __syncthreads(); }

    if (t == 0) {
        float entropy = -red[0];
        int step_after = step_ptr[0] + 1;
        float bonus_w = 0.05f * (1.0f - (float)step_after / 20000.0f);
        float eb = (step_after < 20000) ? (-bonus_w * entropy) : 0.0f;
        out4[0] = commitment;
        out4[1] = eb;
        out4[2] = expf(entropy);
        out4[3] = entropy;
    }
}

extern "C" void kernel_launch(void* const* d_in, const int* in_sizes, int n_in,
                              void* d_out, int out_size, void* d_ws, size_t ws_size,
                              hipStream_t stream)
{
    const float* z     = (const float*)d_in[0];
    const float* u     = (const float*)d_in[1];
    const float* cb    = (const float*)d_in[2];
    const float* usage = (const float*)d_in[3];
    const int*   step  = (const int*)d_in[4];

    float* out  = (float*)d_out;
    float* zq   = out;                 // 4194304
    float* emb  = out + 4194304;       // 4194304
    float* idxo = out + 8388608;       // 16384
    float* scal = out + 8404992;       // 4

    // prep arrays live in d_out's first 20 MB (dead until reduce_gather rewrites it)
    _Float16* zhi = (_Float16*)out;            // 8 MB
    _Float16* zlo = zhi + 4194304;             // 8 MB
    _Float16* chi = zlo + 4194304;             // 2 MB
    _Float16* clo = chi + 1048576;             // 2 MB

    float*  ws          = (float*)d_ws;
    float*  zinv        = ws;                    // 16384
    float*  cinv        = ws + 16384;            // 4096
    float*  commit_part = ws + 20480;            // 16384
    float2* partial     = (float2*)(ws + 36864); // 16384*32 float2 (4 MB)

    hipLaunchKernelGGL(norms_kernel, dim3(5120), dim3(256), 0, stream, z, cb, zinv, cinv);
    hipLaunchKernelGGL(prep_kernel, dim3(8, 128), dim3(256), 0, stream, z,  zinv, zhi, zlo);
    hipLaunchKernelGGL(prep_kernel, dim3(8, 32),  dim3(256), 0, stream, cb, cinv, chi, clo);
    hipLaunchKernelGGL(gemm_argmax_kernel, dim3(4096), dim3(256), 0, stream,
                       zhi, zlo, chi, clo, u, partial);
    hipLaunchKernelGGL(reduce_gather_kernel, dim3(4096), dim3(256), 0, stream,
                       partial, cb, z, zq, emb, idxo, commit_part);
    hipLaunchKernelGGL(scalars_kernel, dim3(1), dim3(256), 0, stream,
                       commit_part, usage, step, scal);
}